// Round 14
// baseline (310.213 us; speedup 1.0000x reference)
//
#include <hip/hip_runtime.h>
#include <hip/hip_fp16.h>
#include <math.h>

#define IN_CH 16
#define HC1 128   // H1*C1
#define NH1 4
#define C2 32
#define HID 64
#define NEG 0.2f
#define CAP 10240     // per-bucket capacity (mean ~8450, +20 sigma)
#define CHUNK 4096    // edges per bucket block

__device__ __forceinline__ float lrelu_exp_fast(float z) {
    float lr = fmaxf(z, NEG * z);   // leaky-relu via max (exact for neg_slope<1)
    return __expf(lr);
}
__device__ __forceinline__ float elu_fast(float v) {
    return v > 0.f ? v : __expf(v) - 1.0f;
}

// v_fma_mix_f32: acc(f32) += f16half(hpack) * w(f32), full f32 fma precision.
__device__ __forceinline__ void fma_mix_lo(float& acc, int hpack, float w) {
    asm("v_fma_mix_f32 %0, %1, %2, %0 op_sel:[0,0,0] op_sel_hi:[1,0,0]"
        : "+v"(acc) : "v"(hpack), "v"(w));
}
__device__ __forceinline__ void fma_mix_hi(float& acc, int hpack, float w) {
    asm("v_fma_mix_f32 %0, %1, %2, %0 op_sel:[1,0,0] op_sel_hi:[1,0,0]"
        : "+v"(acc) : "v"(hpack), "v"(w));
}

// ---- Fused front: bucket-append (blocks [0,nchunk)) + GAT1 linear (rest) ----
// h1s/as1s/ad1s are HEAD-MAJOR: h1s[head][n][32ch fp16], as1s[head][n].
__global__ void k_front(const int* __restrict__ ei, int E, int N, int nchunk,
                        int* __restrict__ cursors, int* __restrict__ buckets,
                        const float* __restrict__ x, const float2* __restrict__ W1v,
                        const float2* __restrict__ att_s2, const float2* __restrict__ att_d2,
                        __half2* __restrict__ h1s, float* __restrict__ as1s, float* __restrict__ ad1s) {
    int bid = blockIdx.x;
    if (bid < nchunk) {
        __shared__ int cnt[256];
        __shared__ int base[256];
        __shared__ int pos[256];
        int t = threadIdx.x;
        int c0 = bid * CHUNK;
        int M = E + N;
        cnt[t] = 0;
        pos[t] = 0;
        __syncthreads();
        int srcv[16], dstv[16];
#pragma unroll
        for (int k = 0; k < 16; ++k) {
            int i = c0 + k * 256 + t;
            int s = -1, d = -1;
            if (i < M) {
                if (i < E) { s = ei[i]; d = ei[E + i]; }
                else       { s = d = i - E; }
                atomicAdd(&cnt[d >> 8], 1);
            }
            srcv[k] = s; dstv[k] = d;
        }
        __syncthreads();
        if (cnt[t] > 0) base[t] = atomicAdd(&cursors[t], cnt[t]);
        __syncthreads();
#pragma unroll
        for (int k = 0; k < 16; ++k) {
            int d = dstv[k];
            if (d >= 0) {
                int b = d >> 8;
                int p = base[b] + atomicAdd(&pos[b], 1);
                buckets[b * CAP + p] = (srcv[k] << 8) | (d & 255);
            }
        }
    } else {
        int wave = threadIdx.x >> 6;
        int lane = threadIdx.x & 63;
        int n = (bid - nchunk) * 4 + wave;
        if (n >= N) return;
        float xv = x[n * IN_CH + (lane & 15)];
        float ax = 0.f, ay = 0.f;
#pragma unroll
        for (int k = 0; k < IN_CH; ++k) {
            float xk = __shfl(xv, k, 16);
            float2 w = W1v[k * 64 + lane];
            ax += xk * w.x;
            ay += xk * w.y;
        }
        int head = lane >> 4;
        h1s[((size_t)head * N + n) * 16 + (lane & 15)] = __floats2half2_rn(ax, ay);
        float2 s2 = att_s2[lane], d2 = att_d2[lane];
        float vs = ax * s2.x + ay * s2.y;
        float vd = ax * d2.x + ay * d2.y;
#pragma unroll
        for (int o = 1; o < 16; o <<= 1) {
            vs += __shfl_xor(vs, o, 64);
            vd += __shfl_xor(vd, o, 64);
        }
        if ((lane & 15) == 0) {
            as1s[(size_t)head * N + n] = vs;
            ad1s[(size_t)head * N + n] = vd;
        }
    }
}

// ---- CSR build: FOUR blocks per bucket (quarters of 64 nodes).
// Each block does the full 256-node histogram/scan (redundant, cheap) and a
// filtered scatter for its quarter -> 4x write parallelism, same layout.
__global__ void k_build(const int* __restrict__ buckets, const int* __restrict__ cursors,
                        int N, int M,
                        int* __restrict__ offsets, int* __restrict__ elist) {
    __shared__ int sc[256];
    __shared__ int deg[256];
    __shared__ int cur[256];
    int b = blockIdx.x >> 2, qq = blockIdx.x & 3;
    int t = threadIdx.x;
    int cv = cursors[t];
    sc[t] = cv;
    __syncthreads();
    for (int o = 1; o < 256; o <<= 1) {
        int a = (t >= o) ? sc[t - o] : 0;
        __syncthreads();
        sc[t] += a;
        __syncthreads();
    }
    int cnt = cursors[b];
    int gbase = sc[b] - cnt;
    int n0 = b << 8;
    const int* bk = buckets + b * CAP;
    deg[t] = 0;
    if (blockIdx.x == 0 && t == 0) offsets[N] = M;
    __syncthreads();
    for (int i = t; i < cnt; i += 256) atomicAdd(&deg[bk[i] & 255], 1);
    __syncthreads();
    int v = deg[t];
    sc[t] = v;
    __syncthreads();
    for (int o = 1; o < 256; o <<= 1) {
        int a = (t >= o) ? sc[t - o] : 0;
        __syncthreads();
        sc[t] += a;
        __syncthreads();
    }
    int excl = sc[t] - v;
    cur[t] = excl;
    if ((t >> 6) == qq && n0 + t < N) offsets[n0 + t] = gbase + excl;
    __syncthreads();
    for (int i = t; i < cnt; i += 256) {
        int e = bk[i];
        int dl = e & 255;
        if ((dl >> 6) == qq) {
            int p = atomicAdd(&cur[dl], 1);
            elist[gbase + p] = e >> 8;
        }
    }
}

// ---- GAT1 aggregation, ONE HEAD PER DISPATCH (phase-separated L2 residency).
// Wave = 4 dsts x (4 edge-slots x 4 chunks of 16B) over 64B head-rows;
// u=4 -> 16 edges in flight per dst. Writes its 64B column of out1.
__global__ void k_agg1h(const int* __restrict__ offsets, const int* __restrict__ elist,
                        const float* __restrict__ as1s, const float* __restrict__ ad1s,
                        const char* __restrict__ h1b, const float* __restrict__ b1,
                        int N, int head, float4* __restrict__ out1q) {
    int t = threadIdx.x;
    int wave = t >> 6;
    int lane = t & 63;
    int g = lane >> 4;            // dst group 0..3
    int sl = (lane >> 2) & 3;     // edge slot 0..3
    int c4 = lane & 3;            // 16B chunk 0..3
    int n = blockIdx.x * 16 + wave * 4 + g;
    if (n >= N) return;
    int lo = offsets[n], hi = offsets[n + 1];
    const float* ash = as1s + (size_t)head * N;
    const char* hb = h1b + (size_t)head * N * 64;
    float adh = ad1s[(size_t)head * N + n];
    unsigned coff = (unsigned)(c4 << 4);
    float acc[8];
#pragma unroll
    for (int j = 0; j < 8; ++j) acc[j] = 0.f;
    float sumw = 0.f;
    for (int e0 = lo; e0 < hi; e0 += 16) {
        unsigned s[4]; bool ok[4]; float z[4]; float4 v[4]; float w[4];
#pragma unroll
        for (int u = 0; u < 4; ++u) {
            int ee = e0 + 4 * u + sl;
            ok[u] = ee < hi;
            s[u] = (unsigned)elist[ok[u] ? ee : lo];
        }
#pragma unroll
        for (int u = 0; u < 4; ++u) {
            z[u] = ash[s[u]];
            v[u] = *(const float4*)(hb + (s[u] * 64u + coff));
        }
#pragma unroll
        for (int u = 0; u < 4; ++u)
            w[u] = ok[u] ? lrelu_exp_fast(z[u] + adh) : 0.f;
#pragma unroll
        for (int u = 0; u < 4; ++u) {
            const int* hp = (const int*)&v[u];
            fma_mix_lo(acc[0], hp[0], w[u]); fma_mix_hi(acc[1], hp[0], w[u]);
            fma_mix_lo(acc[2], hp[1], w[u]); fma_mix_hi(acc[3], hp[1], w[u]);
            fma_mix_lo(acc[4], hp[2], w[u]); fma_mix_hi(acc[5], hp[2], w[u]);
            fma_mix_lo(acc[6], hp[3], w[u]); fma_mix_hi(acc[7], hp[3], w[u]);
            sumw += w[u];
        }
    }
    // reduce across the 4 edge-slots (lane bits 2-3)
#pragma unroll
    for (int j = 0; j < 8; ++j) {
        acc[j] += __shfl_xor(acc[j], 4, 64);
        acc[j] += __shfl_xor(acc[j], 8, 64);
    }
    sumw += __shfl_xor(sumw, 4, 64);
    sumw += __shfl_xor(sumw, 8, 64);
    if (sl == 0) {
        float inv = 1.f / (sumw + 1e-16f);
        const float* bp = b1 + head * 32 + c4 * 8;
        float o[8];
#pragma unroll
        for (int j = 0; j < 8; ++j) o[j] = elu_fast(acc[j] * inv + bp[j]);
        float4 pk;
        __half2* ph = (__half2*)&pk;
        ph[0] = __floats2half2_rn(o[0], o[1]);
        ph[1] = __floats2half2_rn(o[2], o[3]);
        ph[2] = __floats2half2_rn(o[4], o[5]);
        ph[3] = __floats2half2_rn(o[6], o[7]);
        out1q[(size_t)n * 16 + head * 4 + c4] = pk;   // node-major 256B rows
    }
}

// ---- GAT2 linear: LDS-tiled GEMM [N,128](fp16) x [128,32] + logits ----
#define TN 64
__global__ void k_lin2(const __half2* __restrict__ out1h, const float* __restrict__ W2,
                       const float* __restrict__ att_s, const float* __restrict__ att_d,
                       int N, __half2* __restrict__ h2h, float* __restrict__ as2, float* __restrict__ ad2) {
    __shared__ float sx[TN][HC1 + 1];
    __shared__ float sw[HC1][C2];
    int t = threadIdx.x;  // 256
    int base = blockIdx.x * TN;
    int lim = (N - base) * HC1;
    for (int i = t * 4; i < HC1 * C2; i += 1024) {
        float4 v = *(const float4*)(W2 + i);
        sw[i >> 5][i & 31] = v.x;
        sw[i >> 5][(i & 31) + 1] = v.y;
        sw[i >> 5][(i & 31) + 2] = v.z;
        sw[i >> 5][(i & 31) + 3] = v.w;
    }
    for (int i = t * 4; i < TN * HC1; i += 1024) {
        float2 a = make_float2(0.f, 0.f), b = make_float2(0.f, 0.f);
        if (i < lim) {
            size_t idx = ((size_t)base * HC1 + i) >> 1;
            a = __half22float2(out1h[idx]);
            b = __half22float2(out1h[idx + 1]);
        }
        int nn = i >> 7, kk = i & 127;
        sx[nn][kk] = a.x; sx[nn][kk + 1] = a.y; sx[nn][kk + 2] = b.x; sx[nn][kk + 3] = b.y;
    }
    __syncthreads();
    int nloc = t >> 2;
    int c0 = (t & 3) * 8;
    float acc[8];
#pragma unroll
    for (int j = 0; j < 8; ++j) acc[j] = 0.f;
#pragma unroll 4
    for (int k = 0; k < HC1; ++k) {
        float xv = sx[nloc][k];
        float4 wa = *(float4*)&sw[k][c0];
        float4 wb = *(float4*)&sw[k][c0 + 4];
        acc[0] += xv * wa.x; acc[1] += xv * wa.y; acc[2] += xv * wa.z; acc[3] += xv * wa.w;
        acc[4] += xv * wb.x; acc[5] += xv * wb.y; acc[6] += xv * wb.z; acc[7] += xv * wb.w;
    }
    int n = base + nloc;
    if (n < N) {
#pragma unroll
        for (int j = 0; j < 4; ++j)
            h2h[(size_t)n * 16 + (c0 >> 1) + j] = __floats2half2_rn(acc[2 * j], acc[2 * j + 1]);
        float ps = 0.f, pd = 0.f;
#pragma unroll
        for (int j = 0; j < 8; ++j) {
            ps += acc[j] * att_s[c0 + j];
            pd += acc[j] * att_d[c0 + j];
        }
        ps += __shfl_down(ps, 1, 64); ps += __shfl_down(ps, 2, 64);
        pd += __shfl_down(pd, 1, 64); pd += __shfl_down(pd, 2, 64);
        if ((t & 3) == 0) { as2[n] = ps; ad2[n] = pd; }
    }
}

// ---- GAT2 aggregation: one wave per dst; 16 edge-slots x 4 lanes x float4,
//      32 edges in flight; unsigned 32-bit offsets + v_fma_mix ----
__global__ void k_agg2(const int* __restrict__ offsets, const int* __restrict__ elist,
                       const char* __restrict__ as2b, const float* __restrict__ ad2,
                       const char* __restrict__ h2b, const float* __restrict__ b2,
                       int N, float* __restrict__ out2) {
    int wave = threadIdx.x >> 6;
    int lane = threadIdx.x & 63;
    int n = blockIdx.x * 4 + wave;
    if (n >= N) return;
    int slot = lane >> 2, chunk = lane & 3;
    int lo = offsets[n], hi = offsets[n + 1];
    float ad = ad2[n];
    unsigned coff = (unsigned)(chunk << 4);
    float acc[8];
#pragma unroll
    for (int j = 0; j < 8; ++j) acc[j] = 0.f;
    float sumw = 0.f;
    for (int e0 = lo; e0 < hi; e0 += 32) {
        unsigned s[2]; bool ok[2]; float z[2]; float4 v[2]; float w[2];
#pragma unroll
        for (int u = 0; u < 2; ++u) {
            int ee = e0 + 16 * u + slot;
            ok[u] = ee < hi;
            s[u] = (unsigned)elist[ok[u] ? ee : lo];
        }
#pragma unroll
        for (int u = 0; u < 2; ++u) {
            z[u] = *(const float*)(as2b + (s[u] * 4u));
            v[u] = *(const float4*)(h2b + (s[u] * 64u + coff));
        }
#pragma unroll
        for (int u = 0; u < 2; ++u)
            w[u] = ok[u] ? lrelu_exp_fast(z[u] + ad) : 0.f;
#pragma unroll
        for (int u = 0; u < 2; ++u) {
            const int* hp = (const int*)&v[u];
            fma_mix_lo(acc[0], hp[0], w[u]); fma_mix_hi(acc[1], hp[0], w[u]);
            fma_mix_lo(acc[2], hp[1], w[u]); fma_mix_hi(acc[3], hp[1], w[u]);
            fma_mix_lo(acc[4], hp[2], w[u]); fma_mix_hi(acc[5], hp[2], w[u]);
            fma_mix_lo(acc[6], hp[3], w[u]); fma_mix_hi(acc[7], hp[3], w[u]);
            sumw += w[u];
        }
    }
#pragma unroll
    for (int j = 0; j < 8; ++j) {
        acc[j] += __shfl_xor(acc[j], 4, 64);
        acc[j] += __shfl_xor(acc[j], 8, 64);
        acc[j] += __shfl_xor(acc[j], 16, 64);
        acc[j] += __shfl_xor(acc[j], 32, 64);
    }
    sumw += __shfl_xor(sumw, 4, 64);
    sumw += __shfl_xor(sumw, 8, 64);
    sumw += __shfl_xor(sumw, 16, 64);
    sumw += __shfl_xor(sumw, 32, 64);
    if (slot == 0) {
        float inv = 1.f / (sumw + 1e-16f);
        float4 ba = ((const float4*)b2)[2 * chunk];
        float4 bb = ((const float4*)b2)[2 * chunk + 1];
        float o[8];
        o[0] = elu_fast(acc[0] * inv + ba.x); o[1] = elu_fast(acc[1] * inv + ba.y);
        o[2] = elu_fast(acc[2] * inv + ba.z); o[3] = elu_fast(acc[3] * inv + ba.w);
        o[4] = elu_fast(acc[4] * inv + bb.x); o[5] = elu_fast(acc[5] * inv + bb.y);
        o[6] = elu_fast(acc[6] * inv + bb.z); o[7] = elu_fast(acc[7] * inv + bb.w);
        float* dst = out2 + (size_t)n * C2 + 8 * chunk;
        *(float4*)dst = make_float4(o[0], o[1], o[2], o[3]);
        *(float4*)(dst + 4) = make_float4(o[4], o[5], o[6], o[7]);
    }
}

// ---- mean-pool per graph + MLP head ----
__global__ void k_pool(const float* __restrict__ out2, const int* __restrict__ batch,
                       int N, const float* __restrict__ Wh1, const float* __restrict__ bh1,
                       const float* __restrict__ Wh2, const float* __restrict__ bh2,
                       float* __restrict__ out) {
    int g = blockIdx.x;
    int t = threadIdx.x;
    __shared__ int sb[2];
    __shared__ float pooled[C2];
    __shared__ float red[256];
    if (t < 2) {
        int target = g + t;
        int lo = 0, hi = N;
        while (lo < hi) { int mid = (lo + hi) >> 1; if (batch[mid] < target) lo = mid + 1; else hi = mid; }
        sb[t] = lo;
    }
    __syncthreads();
    int lo = sb[0], hi = sb[1];
    int c = t & 31, grp = t >> 5;
    float part = 0.f;
    for (int n = lo + grp; n < hi; n += 8) part += out2[n * C2 + c];
    red[t] = part;
    __syncthreads();
    if (t < 128) red[t] += red[t + 128];
    __syncthreads();
    if (t < 64) red[t] += red[t + 64];
    __syncthreads();
    if (t < 32) {
        red[t] += red[t + 32];
        float cnt = (float)(hi - lo);
        pooled[t] = red[t] / fmaxf(cnt, 1.f);
    }
    __syncthreads();
    float hval = 0.f;
    if (t < HID) {
        float a = bh1[t];
#pragma unroll
        for (int cc = 0; cc < C2; ++cc) a += pooled[cc] * Wh1[cc * HID + t];
        hval = fmaxf(a, 0.f) * Wh2[t];
    }
    if (t < 64) {
        for (int o = 32; o > 0; o >>= 1) hval += __shfl_down(hval, o, 64);
        if (t == 0) out[g] = hval + bh2[0];
    }
}

extern "C" void kernel_launch(void* const* d_in, const int* in_sizes, int n_in,
                              void* d_out, int out_size, void* d_ws, size_t ws_size,
                              hipStream_t stream) {
    const float* x    = (const float*)d_in[0];
    const int*   ei   = (const int*)d_in[1];
    const int*   batch= (const int*)d_in[2];
    const float* W1   = (const float*)d_in[3];
    const float* aS1  = (const float*)d_in[4];
    const float* aD1  = (const float*)d_in[5];
    const float* b1   = (const float*)d_in[6];
    const float* W2   = (const float*)d_in[7];
    const float* aS2  = (const float*)d_in[8];
    const float* aD2  = (const float*)d_in[9];
    const float* b2   = (const float*)d_in[10];
    const float* Wh1  = (const float*)d_in[11];
    const float* bh1  = (const float*)d_in[12];
    const float* Wh2  = (const float*)d_in[13];
    const float* bh2  = (const float*)d_in[14];
    float* out = (float*)d_out;

    int N = in_sizes[2];
    int E = in_sizes[1] / 2;
    int M = E + N;
    int G = out_size;
    int nbk = (N + 255) >> 8;
    int nchunk = (M + CHUNK - 1) / CHUNK;
    int nlin = (N + 3) / 4;

    char* p = (char*)d_ws;
    auto alloc = [&](size_t bytes) -> void* {
        void* r = (void*)p;
        p += (bytes + 255) & ~(size_t)255;
        return r;
    };
    __half2* h1s   = (__half2*)alloc((size_t)N * 64 * 4);   // 4 x [N x 32ch] fp16, head-major
    __half2* out1h = (__half2*)alloc((size_t)N * 64 * 4);   // N x 128 fp16, node-major
    __half2* h2h   = (__half2*)alloc((size_t)N * 16 * 4);   // N x 32 fp16
    float* as1s    = (float*)alloc((size_t)N * NH1 * 4);    // head-major
    float* ad1s    = (float*)alloc((size_t)N * NH1 * 4);    // head-major
    float* as2     = (float*)alloc((size_t)N * 4);
    float* ad2     = (float*)alloc((size_t)N * 4);
    float* out2    = (float*)alloc((size_t)N * C2 * 4);
    int*   offsets = (int*)alloc((size_t)(N + 1) * 4);
    int*   elist   = (int*)alloc((size_t)M * 4);
    int*   cursors = (int*)alloc(256 * 4);
    int*   buckets = (int*)alloc((size_t)nbk * CAP * 4);

    hipMemsetAsync(cursors, 0, 256 * 4, stream);
    k_front<<<nchunk + nlin, 256, 0, stream>>>(ei, E, N, nchunk, cursors, buckets,
                                               x, (const float2*)W1, (const float2*)aS1,
                                               (const float2*)aD1, h1s, as1s, ad1s);
    k_build<<<4 * nbk, 256, 0, stream>>>(buckets, cursors, N, M, offsets, elist);
    int nblk16 = (N + 15) / 16;
    for (int head = 0; head < NH1; ++head) {
        k_agg1h<<<nblk16, 256, 0, stream>>>(offsets, elist, as1s, ad1s,
                                            (const char*)h1s, b1, N, head,
                                            (float4*)out1h);
    }
    k_lin2<<<(N + TN - 1) / TN, 256, 0, stream>>>(out1h, W2, aS2, aD2, N, h2h, as2, ad2);
    k_agg2<<<(N + 3) / 4, 256, 0, stream>>>(offsets, elist, (const char*)as2, ad2,
                                            (const char*)h2h, b2, N, out2);
    k_pool<<<G, 256, 0, stream>>>(out2, batch, N, Wh1, bh1, Wh2, bh2, out);
}

// Round 15
// 283.430 us; speedup vs baseline: 1.0945x; 1.0945x over previous
//
#include <hip/hip_runtime.h>
#include <hip/hip_fp16.h>
#include <math.h>

#define IN_CH 16
#define HC1 128   // H1*C1
#define NH1 4
#define C2 32
#define HID 64
#define NEG 0.2f
#define CAP 10240     // per-bucket capacity (mean ~8450, +20 sigma)
#define CHUNK 2048    // edges per bucket block (8 per thread)

__device__ __forceinline__ float lrelu_exp_fast(float z) {
    float lr = fmaxf(z, NEG * z);   // leaky-relu via max (exact for neg_slope<1)
    return __expf(lr);
}
__device__ __forceinline__ float elu_fast(float v) {
    return v > 0.f ? v : __expf(v) - 1.0f;
}

// v_fma_mix_f32: acc(f32) += f16half(hpack) * w(f32), full f32 fma precision.
__device__ __forceinline__ void fma_mix_lo(float& acc, int hpack, float w) {
    asm("v_fma_mix_f32 %0, %1, %2, %0 op_sel:[0,0,0] op_sel_hi:[1,0,0]"
        : "+v"(acc) : "v"(hpack), "v"(w));
}
__device__ __forceinline__ void fma_mix_hi(float& acc, int hpack, float w) {
    asm("v_fma_mix_f32 %0, %1, %2, %0 op_sel:[1,0,0] op_sel_hi:[1,0,0]"
        : "+v"(acc) : "v"(hpack), "v"(w));
}

// ---- Fused front: bucket-append (blocks [0,nchunk)) + GAT1 linear (rest) ----
// Bucket phase uses ONE LDS atomic per edge (count doubles as local slot).
__global__ void k_front(const int* __restrict__ ei, int E, int N, int nchunk,
                        int* __restrict__ cursors, int* __restrict__ buckets,
                        const float* __restrict__ x, const float2* __restrict__ W1v,
                        const float2* __restrict__ att_s2, const float2* __restrict__ att_d2,
                        __half2* __restrict__ h1h, float* __restrict__ as1, float* __restrict__ ad1) {
    int bid = blockIdx.x;
    if (bid < nchunk) {
        __shared__ int cnt[256];
        __shared__ int base[256];
        int t = threadIdx.x;
        int c0 = bid * CHUNK;
        int M = E + N;
        cnt[t] = 0;
        __syncthreads();
        int srcv[8], dstv[8], lp[8];
#pragma unroll
        for (int k = 0; k < 8; ++k) {
            int i = c0 + k * 256 + t;
            int s = -1, d = -1, l = 0;
            if (i < M) {
                if (i < E) { s = ei[i]; d = ei[E + i]; }
                else       { s = d = i - E; }
                l = atomicAdd(&cnt[d >> 8], 1);   // count == local slot
            }
            srcv[k] = s; dstv[k] = d; lp[k] = l;
        }
        __syncthreads();
        if (cnt[t] > 0) base[t] = atomicAdd(&cursors[t], cnt[t]);
        __syncthreads();
#pragma unroll
        for (int k = 0; k < 8; ++k) {
            int d = dstv[k];
            if (d >= 0) {
                int b = d >> 8;
                buckets[b * CAP + base[b] + lp[k]] = (srcv[k] << 8) | (d & 255);
            }
        }
    } else {
        int wave = threadIdx.x >> 6;
        int lane = threadIdx.x & 63;
        int n = (bid - nchunk) * 4 + wave;
        if (n >= N) return;
        float xv = x[n * IN_CH + (lane & 15)];
        float ax = 0.f, ay = 0.f;
#pragma unroll
        for (int k = 0; k < IN_CH; ++k) {
            float xk = __shfl(xv, k, 16);
            float2 w = W1v[k * 64 + lane];
            ax += xk * w.x;
            ay += xk * w.y;
        }
        h1h[(size_t)n * 64 + lane] = __floats2half2_rn(ax, ay);
        float2 s2 = att_s2[lane], d2 = att_d2[lane];
        float vs = ax * s2.x + ay * s2.y;
        float vd = ax * d2.x + ay * d2.y;
#pragma unroll
        for (int o = 1; o < 16; o <<= 1) {
            vs += __shfl_xor(vs, o, 64);
            vd += __shfl_xor(vd, o, 64);
        }
        if ((lane & 15) == 0) {
            as1[n * NH1 + (lane >> 4)] = vs;
            ad1[n * NH1 + (lane >> 4)] = vd;
        }
    }
}

// ---- CSR build: TWO blocks per bucket (half-buckets of 128 nodes) ----
__global__ void k_build(const int* __restrict__ buckets, const int* __restrict__ cursors,
                        int N, int M,
                        int* __restrict__ offsets, int* __restrict__ elist) {
    __shared__ int sc[256];
    __shared__ int deg[128];
    __shared__ int cur[128];
    int b = blockIdx.x >> 1, half = blockIdx.x & 1;
    int t = threadIdx.x;
    int cv = cursors[t];
    sc[t] = cv;
    __syncthreads();
    for (int o = 1; o < 256; o <<= 1) {
        int a = (t >= o) ? sc[t - o] : 0;
        __syncthreads();
        sc[t] += a;
        __syncthreads();
    }
    int cnt = cursors[b];
    int gbase_bucket = sc[b] - cnt;
    int n0 = (b << 8) + (half << 7);
    const int* bk = buckets + b * CAP;
    if (t < 128) deg[t] = 0;
    if (blockIdx.x == 0 && t == 0) offsets[N] = M;
    __syncthreads();
    for (int i = t; i < cnt; i += 256) {
        int dl = bk[i] & 255;
        if ((dl >> 7) == half) atomicAdd(&deg[dl & 127], 1);
    }
    __syncthreads();
    int v = (t < 128) ? deg[t] : 0;
    if (t < 128) sc[t] = v;
    __syncthreads();
    for (int o = 1; o < 128; o <<= 1) {
        int a = (t < 128 && t >= o) ? sc[t - o] : 0;
        __syncthreads();
        if (t < 128) sc[t] += a;
        __syncthreads();
    }
    __shared__ int gbh;
    if (t == 127) {
        int S = sc[127];
        gbh = (half == 0) ? gbase_bucket : gbase_bucket + (cnt - S);
    }
    __syncthreads();
    int gbase = gbh;
    if (t < 128) {
        int excl = sc[t] - v;
        cur[t] = excl;
        if (n0 + t < N) offsets[n0 + t] = gbase + excl;
    }
    __syncthreads();
    for (int i = t; i < cnt; i += 256) {
        int e = bk[i];
        int dl = e & 255;
        if ((dl >> 7) == half) {
            int p = atomicAdd(&cur[dl & 127], 1);
            elist[gbase + p] = e >> 8;
        }
    }
}

// ---- FUSED GAT1 aggregation + GAT2 linear (R13 config, best total) ----
__global__ void k_agg1(const int* __restrict__ offsets, const int* __restrict__ elist,
                       const char* __restrict__ as1b, const float* __restrict__ ad1,
                       const char* __restrict__ h1b, const float* __restrict__ b1,
                       const float4* __restrict__ W2q,
                       const float* __restrict__ aS2v, const float* __restrict__ aD2v,
                       int N, __half2* __restrict__ h2h,
                       float* __restrict__ as2, float* __restrict__ ad2) {
    __shared__ float4 swz[HC1 * 8];    // W2 float4-slots, kh-rotated (16KB)
    __shared__ float4 sxr[4][32];      // per-wave x row, q^(q>>2) swizzled (2KB)
    int t = threadIdx.x;
    for (int q = t; q < HC1 * 8; q += 256) {
        int k = q >> 3, c4g = q & 7;
        int phys = (q & ~7) | ((c4g + (k >> 4)) & 7);
        swz[phys] = W2q[q];
    }
    __syncthreads();

    int wave = t >> 6;
    int lane = t & 63;
    int n = blockIdx.x * 4 + wave;
    if (n >= N) return;   // no block barriers below

    int slot = lane >> 4, chunk = lane & 15, head = chunk >> 2;
    int lo = offsets[n], hi = offsets[n + 1];
    float adh = ad1[n * NH1 + head];
    unsigned coff = (unsigned)(chunk << 4);
    unsigned hoff = (unsigned)(head << 2);
    float acc[8];
#pragma unroll
    for (int j = 0; j < 8; ++j) acc[j] = 0.f;
    float sumw = 0.f;
    for (int e0 = lo; e0 < hi; e0 += 16) {
        unsigned s[4]; bool ok[4]; float z[4]; float4 v[4]; float w[4];
#pragma unroll
        for (int u = 0; u < 4; ++u) {
            int ee = e0 + 4 * u + slot;
            ok[u] = ee < hi;
            s[u] = (unsigned)elist[ok[u] ? ee : lo];
        }
#pragma unroll
        for (int u = 0; u < 4; ++u) {
            z[u] = *(const float*)(as1b + (s[u] * 16u + hoff));
            v[u] = *(const float4*)(h1b + (s[u] * 256u + coff));
        }
#pragma unroll
        for (int u = 0; u < 4; ++u)
            w[u] = ok[u] ? lrelu_exp_fast(z[u] + adh) : 0.f;
#pragma unroll
        for (int u = 0; u < 4; ++u) {
            const int* hp = (const int*)&v[u];
            fma_mix_lo(acc[0], hp[0], w[u]); fma_mix_hi(acc[1], hp[0], w[u]);
            fma_mix_lo(acc[2], hp[1], w[u]); fma_mix_hi(acc[3], hp[1], w[u]);
            fma_mix_lo(acc[4], hp[2], w[u]); fma_mix_hi(acc[5], hp[2], w[u]);
            fma_mix_lo(acc[6], hp[3], w[u]); fma_mix_hi(acc[7], hp[3], w[u]);
            sumw += w[u];
        }
    }
#pragma unroll
    for (int j = 0; j < 8; ++j) {
        acc[j] += __shfl_xor(acc[j], 16, 64);
        acc[j] += __shfl_xor(acc[j], 32, 64);
    }
    sumw += __shfl_xor(sumw, 16, 64);
    sumw += __shfl_xor(sumw, 32, 64);
    if (slot == 0) {
        float inv = 1.f / (sumw + 1e-16f);
        float4 ba = ((const float4*)b1)[2 * chunk];
        float4 bb = ((const float4*)b1)[2 * chunk + 1];
        float4 oa, ob;
        oa.x = elu_fast(acc[0] * inv + ba.x); oa.y = elu_fast(acc[1] * inv + ba.y);
        oa.z = elu_fast(acc[2] * inv + ba.z); oa.w = elu_fast(acc[3] * inv + ba.w);
        ob.x = elu_fast(acc[4] * inv + bb.x); ob.y = elu_fast(acc[5] * inv + bb.y);
        ob.z = elu_fast(acc[6] * inv + bb.z); ob.w = elu_fast(acc[7] * inv + bb.w);
        int q0 = chunk * 2, q1 = q0 + 1;
        sxr[wave][q0 ^ (q0 >> 2)] = oa;
        sxr[wave][q1 ^ (q1 >> 2)] = ob;
    }
    __builtin_amdgcn_wave_barrier();

    int c4g = lane & 7, kh = lane >> 3;
    int c4 = c4g * 4;
    float g0 = 0.f, g1 = 0.f, g2 = 0.f, g3 = 0.f;
#pragma unroll
    for (int kk4 = 0; kk4 < 4; ++kk4) {
        int qx = kh * 4 + kk4;
        float4 xv = sxr[wave][qx ^ (qx >> 2)];
#pragma unroll
        for (int j = 0; j < 4; ++j) {
            float x1 = (j == 0) ? xv.x : (j == 1) ? xv.y : (j == 2) ? xv.z : xv.w;
            int k = kh * 16 + kk4 * 4 + j;
            float4 wv = swz[(k << 3) | ((c4g + kh) & 7)];
            g0 += x1 * wv.x; g1 += x1 * wv.y; g2 += x1 * wv.z; g3 += x1 * wv.w;
        }
    }
    g0 += __shfl_xor(g0, 8, 64); g0 += __shfl_xor(g0, 16, 64); g0 += __shfl_xor(g0, 32, 64);
    g1 += __shfl_xor(g1, 8, 64); g1 += __shfl_xor(g1, 16, 64); g1 += __shfl_xor(g1, 32, 64);
    g2 += __shfl_xor(g2, 8, 64); g2 += __shfl_xor(g2, 16, 64); g2 += __shfl_xor(g2, 32, 64);
    g3 += __shfl_xor(g3, 8, 64); g3 += __shfl_xor(g3, 16, 64); g3 += __shfl_xor(g3, 32, 64);
    if (lane < 8) {
        h2h[(size_t)n * 16 + (c4 >> 1)]     = __floats2half2_rn(g0, g1);
        h2h[(size_t)n * 16 + (c4 >> 1) + 1] = __floats2half2_rn(g2, g3);
        float ps = g0 * aS2v[c4] + g1 * aS2v[c4 + 1] + g2 * aS2v[c4 + 2] + g3 * aS2v[c4 + 3];
        float pd = g0 * aD2v[c4] + g1 * aD2v[c4 + 1] + g2 * aD2v[c4 + 2] + g3 * aD2v[c4 + 3];
        ps += __shfl_xor(ps, 1, 64); ps += __shfl_xor(ps, 2, 64); ps += __shfl_xor(ps, 4, 64);
        pd += __shfl_xor(pd, 1, 64); pd += __shfl_xor(pd, 2, 64); pd += __shfl_xor(pd, 4, 64);
        if (lane == 0) { as2[n] = ps; ad2[n] = pd; }
    }
}

// ---- GAT2 aggregation: one wave per dst; 16 edge-slots x 4 lanes x float4,
//      32 edges in flight; unsigned 32-bit offsets + v_fma_mix ----
__global__ void k_agg2(const int* __restrict__ offsets, const int* __restrict__ elist,
                       const char* __restrict__ as2b, const float* __restrict__ ad2,
                       const char* __restrict__ h2b, const float* __restrict__ b2,
                       int N, float* __restrict__ out2) {
    int wave = threadIdx.x >> 6;
    int lane = threadIdx.x & 63;
    int n = blockIdx.x * 4 + wave;
    if (n >= N) return;
    int slot = lane >> 2, chunk = lane & 3;
    int lo = offsets[n], hi = offsets[n + 1];
    float ad = ad2[n];
    unsigned coff = (unsigned)(chunk << 4);
    float acc[8];
#pragma unroll
    for (int j = 0; j < 8; ++j) acc[j] = 0.f;
    float sumw = 0.f;
    for (int e0 = lo; e0 < hi; e0 += 32) {
        unsigned s[2]; bool ok[2]; float z[2]; float4 v[2]; float w[2];
#pragma unroll
        for (int u = 0; u < 2; ++u) {
            int ee = e0 + 16 * u + slot;
            ok[u] = ee < hi;
            s[u] = (unsigned)elist[ok[u] ? ee : lo];
        }
#pragma unroll
        for (int u = 0; u < 2; ++u) {
            z[u] = *(const float*)(as2b + (s[u] * 4u));
            v[u] = *(const float4*)(h2b + (s[u] * 64u + coff));
        }
#pragma unroll
        for (int u = 0; u < 2; ++u)
            w[u] = ok[u] ? lrelu_exp_fast(z[u] + ad) : 0.f;
#pragma unroll
        for (int u = 0; u < 2; ++u) {
            const int* hp = (const int*)&v[u];
            fma_mix_lo(acc[0], hp[0], w[u]); fma_mix_hi(acc[1], hp[0], w[u]);
            fma_mix_lo(acc[2], hp[1], w[u]); fma_mix_hi(acc[3], hp[1], w[u]);
            fma_mix_lo(acc[4], hp[2], w[u]); fma_mix_hi(acc[5], hp[2], w[u]);
            fma_mix_lo(acc[6], hp[3], w[u]); fma_mix_hi(acc[7], hp[3], w[u]);
            sumw += w[u];
        }
    }
#pragma unroll
    for (int j = 0; j < 8; ++j) {
        acc[j] += __shfl_xor(acc[j], 4, 64);
        acc[j] += __shfl_xor(acc[j], 8, 64);
        acc[j] += __shfl_xor(acc[j], 16, 64);
        acc[j] += __shfl_xor(acc[j], 32, 64);
    }
    sumw += __shfl_xor(sumw, 4, 64);
    sumw += __shfl_xor(sumw, 8, 64);
    sumw += __shfl_xor(sumw, 16, 64);
    sumw += __shfl_xor(sumw, 32, 64);
    if (slot == 0) {
        float inv = 1.f / (sumw + 1e-16f);
        float4 ba = ((const float4*)b2)[2 * chunk];
        float4 bb = ((const float4*)b2)[2 * chunk + 1];
        float o[8];
        o[0] = elu_fast(acc[0] * inv + ba.x); o[1] = elu_fast(acc[1] * inv + ba.y);
        o[2] = elu_fast(acc[2] * inv + ba.z); o[3] = elu_fast(acc[3] * inv + ba.w);
        o[4] = elu_fast(acc[4] * inv + bb.x); o[5] = elu_fast(acc[5] * inv + bb.y);
        o[6] = elu_fast(acc[6] * inv + bb.z); o[7] = elu_fast(acc[7] * inv + bb.w);
        float* dst = out2 + (size_t)n * C2 + 8 * chunk;
        *(float4*)dst = make_float4(o[0], o[1], o[2], o[3]);
        *(float4*)(dst + 4) = make_float4(o[4], o[5], o[6], o[7]);
    }
}

// ---- mean-pool per graph + MLP head ----
__global__ void k_pool(const float* __restrict__ out2, const int* __restrict__ batch,
                       int N, const float* __restrict__ Wh1, const float* __restrict__ bh1,
                       const float* __restrict__ Wh2, const float* __restrict__ bh2,
                       float* __restrict__ out) {
    int g = blockIdx.x;
    int t = threadIdx.x;
    __shared__ int sb[2];
    __shared__ float pooled[C2];
    __shared__ float red[256];
    if (t < 2) {
        int target = g + t;
        int lo = 0, hi = N;
        while (lo < hi) { int mid = (lo + hi) >> 1; if (batch[mid] < target) lo = mid + 1; else hi = mid; }
        sb[t] = lo;
    }
    __syncthreads();
    int lo = sb[0], hi = sb[1];
    int c = t & 31, grp = t >> 5;
    float part = 0.f;
    for (int n = lo + grp; n < hi; n += 8) part += out2[n * C2 + c];
    red[t] = part;
    __syncthreads();
    if (t < 128) red[t] += red[t + 128];
    __syncthreads();
    if (t < 64) red[t] += red[t + 64];
    __syncthreads();
    if (t < 32) {
        red[t] += red[t + 32];
        float cnt = (float)(hi - lo);
        pooled[t] = red[t] / fmaxf(cnt, 1.f);
    }
    __syncthreads();
    float hval = 0.f;
    if (t < HID) {
        float a = bh1[t];
#pragma unroll
        for (int cc = 0; cc < C2; ++cc) a += pooled[cc] * Wh1[cc * HID + t];
        hval = fmaxf(a, 0.f) * Wh2[t];
    }
    if (t < 64) {
        for (int o = 32; o > 0; o >>= 1) hval += __shfl_down(hval, o, 64);
        if (t == 0) out[g] = hval + bh2[0];
    }
}

extern "C" void kernel_launch(void* const* d_in, const int* in_sizes, int n_in,
                              void* d_out, int out_size, void* d_ws, size_t ws_size,
                              hipStream_t stream) {
    const float* x    = (const float*)d_in[0];
    const int*   ei   = (const int*)d_in[1];
    const int*   batch= (const int*)d_in[2];
    const float* W1   = (const float*)d_in[3];
    const float* aS1  = (const float*)d_in[4];
    const float* aD1  = (const float*)d_in[5];
    const float* b1   = (const float*)d_in[6];
    const float* W2   = (const float*)d_in[7];
    const float* aS2  = (const float*)d_in[8];
    const float* aD2  = (const float*)d_in[9];
    const float* b2   = (const float*)d_in[10];
    const float* Wh1  = (const float*)d_in[11];
    const float* bh1  = (const float*)d_in[12];
    const float* Wh2  = (const float*)d_in[13];
    const float* bh2  = (const float*)d_in[14];
    float* out = (float*)d_out;

    int N = in_sizes[2];
    int E = in_sizes[1] / 2;
    int M = E + N;
    int G = out_size;
    int nbk = (N + 255) >> 8;
    int nchunk = (M + CHUNK - 1) / CHUNK;
    int nlin = (N + 3) / 4;

    char* p = (char*)d_ws;
    auto alloc = [&](size_t bytes) -> void* {
        void* r = (void*)p;
        p += (bytes + 255) & ~(size_t)255;
        return r;
    };
    __half2* h1h   = (__half2*)alloc((size_t)N * 64 * 4);   // N x 128 fp16, node-major
    __half2* h2h   = (__half2*)alloc((size_t)N * 16 * 4);   // N x 32 fp16
    float* as1     = (float*)alloc((size_t)N * NH1 * 4);
    float* ad1     = (float*)alloc((size_t)N * NH1 * 4);
    float* as2     = (float*)alloc((size_t)N * 4);
    float* ad2     = (float*)alloc((size_t)N * 4);
    float* out2    = (float*)alloc((size_t)N * C2 * 4);
    int*   offsets = (int*)alloc((size_t)(N + 1) * 4);
    int*   elist   = (int*)alloc((size_t)M * 4);
    int*   cursors = (int*)alloc(256 * 4);
    int*   buckets = (int*)alloc((size_t)nbk * CAP * 4);

    hipMemsetAsync(cursors, 0, 256 * 4, stream);
    k_front<<<nchunk + nlin, 256, 0, stream>>>(ei, E, N, nchunk, cursors, buckets,
                                               x, (const float2*)W1, (const float2*)aS1,
                                               (const float2*)aD1, h1h, as1, ad1);
    k_build<<<2 * nbk, 256, 0, stream>>>(buckets, cursors, N, M, offsets, elist);
    k_agg1<<<(N + 3) / 4, 256, 0, stream>>>(offsets, elist, (const char*)as1, ad1,
                                            (const char*)h1h, b1, (const float4*)W2,
                                            aS2, aD2, N, h2h, as2, ad2);
    k_agg2<<<(N + 3) / 4, 256, 0, stream>>>(offsets, elist, (const char*)as2, ad2,
                                            (const char*)h2h, b2, N, out2);
    k_pool<<<G, 256, 0, stream>>>(out2, batch, N, Wh1, bh1, Wh2, bh2, out);
}

// Round 16
// 272.746 us; speedup vs baseline: 1.1374x; 1.0392x over previous
//
#include <hip/hip_runtime.h>
#include <hip/hip_fp16.h>
#include <math.h>

#define IN_CH 16
#define HC1 128   // H1*C1
#define NH1 4
#define C2 32
#define HID 64
#define NEG 0.2f
#define CAP 10240     // per-bucket capacity (mean ~8450, +20 sigma)
#define CHUNK 4096    // edges per bucket block (16 per thread)

__device__ __forceinline__ float lrelu_exp_fast(float z) {
    float lr = fmaxf(z, NEG * z);   // leaky-relu via max (exact for neg_slope<1)
    return __expf(lr);
}
__device__ __forceinline__ float elu_fast(float v) {
    return v > 0.f ? v : __expf(v) - 1.0f;
}

// v_fma_mix_f32: acc(f32) += f16half(hpack) * w(f32), full f32 fma precision.
__device__ __forceinline__ void fma_mix_lo(float& acc, int hpack, float w) {
    asm("v_fma_mix_f32 %0, %1, %2, %0 op_sel:[0,0,0] op_sel_hi:[1,0,0]"
        : "+v"(acc) : "v"(hpack), "v"(w));
}
__device__ __forceinline__ void fma_mix_hi(float& acc, int hpack, float w) {
    asm("v_fma_mix_f32 %0, %1, %2, %0 op_sel:[1,0,0] op_sel_hi:[1,0,0]"
        : "+v"(acc) : "v"(hpack), "v"(w));
}

// ---- Fused front: bucket-append (blocks [0,nchunk)) + GAT1 linear (rest) ----
// Bucket phase uses ONE LDS atomic per edge (count doubles as local slot);
// CHUNK=4096 keeps R13's cursor-contention / tail-line geometry.
__global__ void k_front(const int* __restrict__ ei, int E, int N, int nchunk,
                        int* __restrict__ cursors, int* __restrict__ buckets,
                        const float* __restrict__ x, const float2* __restrict__ W1v,
                        const float2* __restrict__ att_s2, const float2* __restrict__ att_d2,
                        __half2* __restrict__ h1h, float* __restrict__ as1, float* __restrict__ ad1) {
    int bid = blockIdx.x;
    if (bid < nchunk) {
        __shared__ int cnt[256];
        __shared__ int base[256];
        int t = threadIdx.x;
        int c0 = bid * CHUNK;
        int M = E + N;
        cnt[t] = 0;
        __syncthreads();
        int srcv[16], dstv[16], lp[16];
#pragma unroll
        for (int k = 0; k < 16; ++k) {
            int i = c0 + k * 256 + t;
            int s = -1, d = -1, l = 0;
            if (i < M) {
                if (i < E) { s = ei[i]; d = ei[E + i]; }
                else       { s = d = i - E; }
                l = atomicAdd(&cnt[d >> 8], 1);   // count == local slot
            }
            srcv[k] = s; dstv[k] = d; lp[k] = l;
        }
        __syncthreads();
        if (cnt[t] > 0) base[t] = atomicAdd(&cursors[t], cnt[t]);
        __syncthreads();
#pragma unroll
        for (int k = 0; k < 16; ++k) {
            int d = dstv[k];
            if (d >= 0) {
                int b = d >> 8;
                buckets[b * CAP + base[b] + lp[k]] = (srcv[k] << 8) | (d & 255);
            }
        }
    } else {
        int wave = threadIdx.x >> 6;
        int lane = threadIdx.x & 63;
        int n = (bid - nchunk) * 4 + wave;
        if (n >= N) return;
        float xv = x[n * IN_CH + (lane & 15)];
        float ax = 0.f, ay = 0.f;
#pragma unroll
        for (int k = 0; k < IN_CH; ++k) {
            float xk = __shfl(xv, k, 16);
            float2 w = W1v[k * 64 + lane];
            ax += xk * w.x;
            ay += xk * w.y;
        }
        h1h[(size_t)n * 64 + lane] = __floats2half2_rn(ax, ay);
        float2 s2 = att_s2[lane], d2 = att_d2[lane];
        float vs = ax * s2.x + ay * s2.y;
        float vd = ax * d2.x + ay * d2.y;
#pragma unroll
        for (int o = 1; o < 16; o <<= 1) {
            vs += __shfl_xor(vs, o, 64);
            vd += __shfl_xor(vd, o, 64);
        }
        if ((lane & 15) == 0) {
            as1[n * NH1 + (lane >> 4)] = vs;
            ad1[n * NH1 + (lane >> 4)] = vd;
        }
    }
}

// ---- CSR build: TWO blocks per bucket (half-buckets of 128 nodes) ----
__global__ void k_build(const int* __restrict__ buckets, const int* __restrict__ cursors,
                        int N, int M,
                        int* __restrict__ offsets, int* __restrict__ elist) {
    __shared__ int sc[256];
    __shared__ int deg[128];
    __shared__ int cur[128];
    int b = blockIdx.x >> 1, half = blockIdx.x & 1;
    int t = threadIdx.x;
    int cv = cursors[t];
    sc[t] = cv;
    __syncthreads();
    for (int o = 1; o < 256; o <<= 1) {
        int a = (t >= o) ? sc[t - o] : 0;
        __syncthreads();
        sc[t] += a;
        __syncthreads();
    }
    int cnt = cursors[b];
    int gbase_bucket = sc[b] - cnt;
    int n0 = (b << 8) + (half << 7);
    const int* bk = buckets + b * CAP;
    if (t < 128) deg[t] = 0;
    if (blockIdx.x == 0 && t == 0) offsets[N] = M;
    __syncthreads();
    for (int i = t; i < cnt; i += 256) {
        int dl = bk[i] & 255;
        if ((dl >> 7) == half) atomicAdd(&deg[dl & 127], 1);
    }
    __syncthreads();
    int v = (t < 128) ? deg[t] : 0;
    if (t < 128) sc[t] = v;
    __syncthreads();
    for (int o = 1; o < 128; o <<= 1) {
        int a = (t < 128 && t >= o) ? sc[t - o] : 0;
        __syncthreads();
        if (t < 128) sc[t] += a;
        __syncthreads();
    }
    __shared__ int gbh;
    if (t == 127) {
        int S = sc[127];
        gbh = (half == 0) ? gbase_bucket : gbase_bucket + (cnt - S);
    }
    __syncthreads();
    int gbase = gbh;
    if (t < 128) {
        int excl = sc[t] - v;
        cur[t] = excl;
        if (n0 + t < N) offsets[n0 + t] = gbase + excl;
    }
    __syncthreads();
    for (int i = t; i < cnt; i += 256) {
        int e = bk[i];
        int dl = e & 255;
        if ((dl >> 7) == half) {
            int p = atomicAdd(&cur[dl & 127], 1);
            elist[gbase + p] = e >> 8;
        }
    }
}

// ---- FUSED GAT1 aggregation + GAT2 linear (R13 config, best total) ----
__global__ void k_agg1(const int* __restrict__ offsets, const int* __restrict__ elist,
                       const char* __restrict__ as1b, const float* __restrict__ ad1,
                       const char* __restrict__ h1b, const float* __restrict__ b1,
                       const float4* __restrict__ W2q,
                       const float* __restrict__ aS2v, const float* __restrict__ aD2v,
                       int N, __half2* __restrict__ h2h,
                       float* __restrict__ as2, float* __restrict__ ad2) {
    __shared__ float4 swz[HC1 * 8];    // W2 float4-slots, kh-rotated (16KB)
    __shared__ float4 sxr[4][32];      // per-wave x row, q^(q>>2) swizzled (2KB)
    int t = threadIdx.x;
    for (int q = t; q < HC1 * 8; q += 256) {
        int k = q >> 3, c4g = q & 7;
        int phys = (q & ~7) | ((c4g + (k >> 4)) & 7);
        swz[phys] = W2q[q];
    }
    __syncthreads();

    int wave = t >> 6;
    int lane = t & 63;
    int n = blockIdx.x * 4 + wave;
    if (n >= N) return;   // no block barriers below

    int slot = lane >> 4, chunk = lane & 15, head = chunk >> 2;
    int lo = offsets[n], hi = offsets[n + 1];
    float adh = ad1[n * NH1 + head];
    unsigned coff = (unsigned)(chunk << 4);
    unsigned hoff = (unsigned)(head << 2);
    float acc[8];
#pragma unroll
    for (int j = 0; j < 8; ++j) acc[j] = 0.f;
    float sumw = 0.f;
    for (int e0 = lo; e0 < hi; e0 += 16) {
        unsigned s[4]; bool ok[4]; float z[4]; float4 v[4]; float w[4];
#pragma unroll
        for (int u = 0; u < 4; ++u) {
            int ee = e0 + 4 * u + slot;
            ok[u] = ee < hi;
            s[u] = (unsigned)elist[ok[u] ? ee : lo];
        }
#pragma unroll
        for (int u = 0; u < 4; ++u) {
            z[u] = *(const float*)(as1b + (s[u] * 16u + hoff));
            v[u] = *(const float4*)(h1b + (s[u] * 256u + coff));
        }
#pragma unroll
        for (int u = 0; u < 4; ++u)
            w[u] = ok[u] ? lrelu_exp_fast(z[u] + adh) : 0.f;
#pragma unroll
        for (int u = 0; u < 4; ++u) {
            const int* hp = (const int*)&v[u];
            fma_mix_lo(acc[0], hp[0], w[u]); fma_mix_hi(acc[1], hp[0], w[u]);
            fma_mix_lo(acc[2], hp[1], w[u]); fma_mix_hi(acc[3], hp[1], w[u]);
            fma_mix_lo(acc[4], hp[2], w[u]); fma_mix_hi(acc[5], hp[2], w[u]);
            fma_mix_lo(acc[6], hp[3], w[u]); fma_mix_hi(acc[7], hp[3], w[u]);
            sumw += w[u];
        }
    }
#pragma unroll
    for (int j = 0; j < 8; ++j) {
        acc[j] += __shfl_xor(acc[j], 16, 64);
        acc[j] += __shfl_xor(acc[j], 32, 64);
    }
    sumw += __shfl_xor(sumw, 16, 64);
    sumw += __shfl_xor(sumw, 32, 64);
    if (slot == 0) {
        float inv = 1.f / (sumw + 1e-16f);
        float4 ba = ((const float4*)b1)[2 * chunk];
        float4 bb = ((const float4*)b1)[2 * chunk + 1];
        float4 oa, ob;
        oa.x = elu_fast(acc[0] * inv + ba.x); oa.y = elu_fast(acc[1] * inv + ba.y);
        oa.z = elu_fast(acc[2] * inv + ba.z); oa.w = elu_fast(acc[3] * inv + ba.w);
        ob.x = elu_fast(acc[4] * inv + bb.x); ob.y = elu_fast(acc[5] * inv + bb.y);
        ob.z = elu_fast(acc[6] * inv + bb.z); ob.w = elu_fast(acc[7] * inv + bb.w);
        int q0 = chunk * 2, q1 = q0 + 1;
        sxr[wave][q0 ^ (q0 >> 2)] = oa;
        sxr[wave][q1 ^ (q1 >> 2)] = ob;
    }
    __builtin_amdgcn_wave_barrier();

    int c4g = lane & 7, kh = lane >> 3;
    int c4 = c4g * 4;
    float g0 = 0.f, g1 = 0.f, g2 = 0.f, g3 = 0.f;
#pragma unroll
    for (int kk4 = 0; kk4 < 4; ++kk4) {
        int qx = kh * 4 + kk4;
        float4 xv = sxr[wave][qx ^ (qx >> 2)];
#pragma unroll
        for (int j = 0; j < 4; ++j) {
            float x1 = (j == 0) ? xv.x : (j == 1) ? xv.y : (j == 2) ? xv.z : xv.w;
            int k = kh * 16 + kk4 * 4 + j;
            float4 wv = swz[(k << 3) | ((c4g + kh) & 7)];
            g0 += x1 * wv.x; g1 += x1 * wv.y; g2 += x1 * wv.z; g3 += x1 * wv.w;
        }
    }
    g0 += __shfl_xor(g0, 8, 64); g0 += __shfl_xor(g0, 16, 64); g0 += __shfl_xor(g0, 32, 64);
    g1 += __shfl_xor(g1, 8, 64); g1 += __shfl_xor(g1, 16, 64); g1 += __shfl_xor(g1, 32, 64);
    g2 += __shfl_xor(g2, 8, 64); g2 += __shfl_xor(g2, 16, 64); g2 += __shfl_xor(g2, 32, 64);
    g3 += __shfl_xor(g3, 8, 64); g3 += __shfl_xor(g3, 16, 64); g3 += __shfl_xor(g3, 32, 64);
    if (lane < 8) {
        h2h[(size_t)n * 16 + (c4 >> 1)]     = __floats2half2_rn(g0, g1);
        h2h[(size_t)n * 16 + (c4 >> 1) + 1] = __floats2half2_rn(g2, g3);
        float ps = g0 * aS2v[c4] + g1 * aS2v[c4 + 1] + g2 * aS2v[c4 + 2] + g3 * aS2v[c4 + 3];
        float pd = g0 * aD2v[c4] + g1 * aD2v[c4 + 1] + g2 * aD2v[c4 + 2] + g3 * aD2v[c4 + 3];
        ps += __shfl_xor(ps, 1, 64); ps += __shfl_xor(ps, 2, 64); ps += __shfl_xor(ps, 4, 64);
        pd += __shfl_xor(pd, 1, 64); pd += __shfl_xor(pd, 2, 64); pd += __shfl_xor(pd, 4, 64);
        if (lane == 0) { as2[n] = ps; ad2[n] = pd; }
    }
}

// ---- GAT2 aggregation: one wave per dst; 16 edge-slots x 4 lanes x float4,
//      32 edges in flight; unsigned 32-bit offsets + v_fma_mix ----
__global__ void k_agg2(const int* __restrict__ offsets, const int* __restrict__ elist,
                       const char* __restrict__ as2b, const float* __restrict__ ad2,
                       const char* __restrict__ h2b, const float* __restrict__ b2,
                       int N, float* __restrict__ out2) {
    int wave = threadIdx.x >> 6;
    int lane = threadIdx.x & 63;
    int n = blockIdx.x * 4 + wave;
    if (n >= N) return;
    int slot = lane >> 2, chunk = lane & 3;
    int lo = offsets[n], hi = offsets[n + 1];
    float ad = ad2[n];
    unsigned coff = (unsigned)(chunk << 4);
    float acc[8];
#pragma unroll
    for (int j = 0; j < 8; ++j) acc[j] = 0.f;
    float sumw = 0.f;
    for (int e0 = lo; e0 < hi; e0 += 32) {
        unsigned s[2]; bool ok[2]; float z[2]; float4 v[2]; float w[2];
#pragma unroll
        for (int u = 0; u < 2; ++u) {
            int ee = e0 + 16 * u + slot;
            ok[u] = ee < hi;
            s[u] = (unsigned)elist[ok[u] ? ee : lo];
        }
#pragma unroll
        for (int u = 0; u < 2; ++u) {
            z[u] = *(const float*)(as2b + (s[u] * 4u));
            v[u] = *(const float4*)(h2b + (s[u] * 64u + coff));
        }
#pragma unroll
        for (int u = 0; u < 2; ++u)
            w[u] = ok[u] ? lrelu_exp_fast(z[u] + ad) : 0.f;
#pragma unroll
        for (int u = 0; u < 2; ++u) {
            const int* hp = (const int*)&v[u];
            fma_mix_lo(acc[0], hp[0], w[u]); fma_mix_hi(acc[1], hp[0], w[u]);
            fma_mix_lo(acc[2], hp[1], w[u]); fma_mix_hi(acc[3], hp[1], w[u]);
            fma_mix_lo(acc[4], hp[2], w[u]); fma_mix_hi(acc[5], hp[2], w[u]);
            fma_mix_lo(acc[6], hp[3], w[u]); fma_mix_hi(acc[7], hp[3], w[u]);
            sumw += w[u];
        }
    }
#pragma unroll
    for (int j = 0; j < 8; ++j) {
        acc[j] += __shfl_xor(acc[j], 4, 64);
        acc[j] += __shfl_xor(acc[j], 8, 64);
        acc[j] += __shfl_xor(acc[j], 16, 64);
        acc[j] += __shfl_xor(acc[j], 32, 64);
    }
    sumw += __shfl_xor(sumw, 4, 64);
    sumw += __shfl_xor(sumw, 8, 64);
    sumw += __shfl_xor(sumw, 16, 64);
    sumw += __shfl_xor(sumw, 32, 64);
    if (slot == 0) {
        float inv = 1.f / (sumw + 1e-16f);
        float4 ba = ((const float4*)b2)[2 * chunk];
        float4 bb = ((const float4*)b2)[2 * chunk + 1];
        float o[8];
        o[0] = elu_fast(acc[0] * inv + ba.x); o[1] = elu_fast(acc[1] * inv + ba.y);
        o[2] = elu_fast(acc[2] * inv + ba.z); o[3] = elu_fast(acc[3] * inv + ba.w);
        o[4] = elu_fast(acc[4] * inv + bb.x); o[5] = elu_fast(acc[5] * inv + bb.y);
        o[6] = elu_fast(acc[6] * inv + bb.z); o[7] = elu_fast(acc[7] * inv + bb.w);
        float* dst = out2 + (size_t)n * C2 + 8 * chunk;
        *(float4*)dst = make_float4(o[0], o[1], o[2], o[3]);
        *(float4*)(dst + 4) = make_float4(o[4], o[5], o[6], o[7]);
    }
}

// ---- mean-pool per graph + MLP head ----
__global__ void k_pool(const float* __restrict__ out2, const int* __restrict__ batch,
                       int N, const float* __restrict__ Wh1, const float* __restrict__ bh1,
                       const float* __restrict__ Wh2, const float* __restrict__ bh2,
                       float* __restrict__ out) {
    int g = blockIdx.x;
    int t = threadIdx.x;
    __shared__ int sb[2];
    __shared__ float pooled[C2];
    __shared__ float red[256];
    if (t < 2) {
        int target = g + t;
        int lo = 0, hi = N;
        while (lo < hi) { int mid = (lo + hi) >> 1; if (batch[mid] < target) lo = mid + 1; else hi = mid; }
        sb[t] = lo;
    }
    __syncthreads();
    int lo = sb[0], hi = sb[1];
    int c = t & 31, grp = t >> 5;
    float part = 0.f;
    for (int n = lo + grp; n < hi; n += 8) part += out2[n * C2 + c];
    red[t] = part;
    __syncthreads();
    if (t < 128) red[t] += red[t + 128];
    __syncthreads();
    if (t < 64) red[t] += red[t + 64];
    __syncthreads();
    if (t < 32) {
        red[t] += red[t + 32];
        float cnt = (float)(hi - lo);
        pooled[t] = red[t] / fmaxf(cnt, 1.f);
    }
    __syncthreads();
    float hval = 0.f;
    if (t < HID) {
        float a = bh1[t];
#pragma unroll
        for (int cc = 0; cc < C2; ++cc) a += pooled[cc] * Wh1[cc * HID + t];
        hval = fmaxf(a, 0.f) * Wh2[t];
    }
    if (t < 64) {
        for (int o = 32; o > 0; o >>= 1) hval += __shfl_down(hval, o, 64);
        if (t == 0) out[g] = hval + bh2[0];
    }
}

extern "C" void kernel_launch(void* const* d_in, const int* in_sizes, int n_in,
                              void* d_out, int out_size, void* d_ws, size_t ws_size,
                              hipStream_t stream) {
    const float* x    = (const float*)d_in[0];
    const int*   ei   = (const int*)d_in[1];
    const int*   batch= (const int*)d_in[2];
    const float* W1   = (const float*)d_in[3];
    const float* aS1  = (const float*)d_in[4];
    const float* aD1  = (const float*)d_in[5];
    const float* b1   = (const float*)d_in[6];
    const float* W2   = (const float*)d_in[7];
    const float* aS2  = (const float*)d_in[8];
    const float* aD2  = (const float*)d_in[9];
    const float* b2   = (const float*)d_in[10];
    const float* Wh1  = (const float*)d_in[11];
    const float* bh1  = (const float*)d_in[12];
    const float* Wh2  = (const float*)d_in[13];
    const float* bh2  = (const float*)d_in[14];
    float* out = (float*)d_out;

    int N = in_sizes[2];
    int E = in_sizes[1] / 2;
    int M = E + N;
    int G = out_size;
    int nbk = (N + 255) >> 8;
    int nchunk = (M + CHUNK - 1) / CHUNK;
    int nlin = (N + 3) / 4;

    char* p = (char*)d_ws;
    auto alloc = [&](size_t bytes) -> void* {
        void* r = (void*)p;
        p += (bytes + 255) & ~(size_t)255;
        return r;
    };
    __half2* h1h   = (__half2*)alloc((size_t)N * 64 * 4);   // N x 128 fp16, node-major
    __half2* h2h   = (__half2*)alloc((size_t)N * 16 * 4);   // N x 32 fp16
    float* as1     = (float*)alloc((size_t)N * NH1 * 4);
    float* ad1     = (float*)alloc((size_t)N * NH1 * 4);
    float* as2     = (float*)alloc((size_t)N * 4);
    float* ad2     = (float*)alloc((size_t)N * 4);
    float* out2    = (float*)alloc((size_t)N * C2 * 4);
    int*   offsets = (int*)alloc((size_t)(N + 1) * 4);
    int*   elist   = (int*)alloc((size_t)M * 4);
    int*   cursors = (int*)alloc(256 * 4);
    int*   buckets = (int*)alloc((size_t)nbk * CAP * 4);

    hipMemsetAsync(cursors, 0, 256 * 4, stream);
    k_front<<<nchunk + nlin, 256, 0, stream>>>(ei, E, N, nchunk, cursors, buckets,
                                               x, (const float2*)W1, (const float2*)aS1,
                                               (const float2*)aD1, h1h, as1, ad1);
    k_build<<<2 * nbk, 256, 0, stream>>>(buckets, cursors, N, M, offsets, elist);
    k_agg1<<<(N + 3) / 4, 256, 0, stream>>>(offsets, elist, (const char*)as1, ad1,
                                            (const char*)h1h, b1, (const float4*)W2,
                                            aS2, aD2, N, h2h, as2, ad2);
    k_agg2<<<(N + 3) / 4, 256, 0, stream>>>(offsets, elist, (const char*)as2, ad2,
                                            (const char*)h2h, b2, N, out2);
    k_pool<<<G, 256, 0, stream>>>(out2, batch, N, Wh1, bh1, Wh2, bh2, out);
}